// Round 4
// baseline (1864.901 us; speedup 1.0000x reference)
//
#include <hip/hip_runtime.h>
#include <hip/hip_bf16.h>

#define BB 128   // batch
#define TT 512   // time
#define EE 100   // embed dim
#define HH 128   // hidden
#define G4 512   // 4*H
#define KK 12    // tags

typedef short bf16x8 __attribute__((ext_vector_type(8)));
typedef float f32x4  __attribute__((ext_vector_type(4)));

__device__ __forceinline__ unsigned short f2bf(float x) {
  __hip_bfloat16 h = __float2bfloat16(x);
  return *reinterpret_cast<unsigned short*>(&h);
}

__device__ __forceinline__ bf16x8 load8_bf(const float* p) {
  float4 a = *reinterpret_cast<const float4*>(p);
  float4 b = *reinterpret_cast<const float4*>(p + 4);
  bf16x8 r;
  r[0] = (short)f2bf(a.x); r[1] = (short)f2bf(a.y);
  r[2] = (short)f2bf(a.z); r[3] = (short)f2bf(a.w);
  r[4] = (short)f2bf(b.x); r[5] = (short)f2bf(b.y);
  r[6] = (short)f2bf(b.z); r[7] = (short)f2bf(b.w);
  return r;
}

__device__ __forceinline__ float fsig(float x) {
  return 1.0f / (1.0f + __expf(-x));
}

// swizzled ushort index for h[b][k] bf16: byte = b*256 + ((k*2) ^ ((b&7)<<4))
__device__ __forceinline__ int hswz(int b, int k) {
  return b * 128 + ((((k * 2) ^ ((b & 7) << 4))) >> 1);
}

// ---------------------------------------------------------------------------
// Kernel 1: pregates  P[t][g][b] = bih[g]+bhh[g] + sum_e x[b,t,e]*Wih[g,e]
// grid = T blocks, 512 threads (one per gate g)
// ---------------------------------------------------------------------------
__global__ __launch_bounds__(512, 2) void pregates_kernel(
    const int* __restrict__ sent, const float* __restrict__ embed,
    const float* __restrict__ Wih, const float* __restrict__ bih,
    const float* __restrict__ bhh, float* __restrict__ P)
{
  __shared__ __align__(16) float4 xt[BB][EE / 4];   // 51.2 KB
  const int t = blockIdx.x;
  const int g = threadIdx.x;

  for (int idx = threadIdx.x; idx < BB * (EE / 4); idx += 512) {
    int r = idx / (EE / 4);
    int k = idx - r * (EE / 4);
    const float4* src =
        reinterpret_cast<const float4*>(embed + (size_t)sent[r * TT + t] * EE);
    xt[r][k] = src[k];
  }

  float4 w[EE / 4];
  const float4* wrow = reinterpret_cast<const float4*>(Wih + (size_t)g * EE);
  #pragma unroll
  for (int k = 0; k < EE / 4; ++k) w[k] = wrow[k];
  const float bias = bih[g] + bhh[g];
  __syncthreads();

  float* outp = P + ((size_t)t * G4 + g) * BB;
  for (int r = 0; r < BB; r += 2) {
    float a0 = 0.f, b0 = 0.f, a1 = 0.f, b1 = 0.f;
    #pragma unroll
    for (int k = 0; k < EE / 4; ++k) {
      float4 e0 = xt[r][k];
      float4 e1 = xt[r + 1][k];
      a0 += w[k].x * e0.x + w[k].y * e0.y;
      b0 += w[k].z * e0.z + w[k].w * e0.w;
      a1 += w[k].x * e1.x + w[k].y * e1.y;
      b1 += w[k].z * e1.z + w[k].w * e1.w;
    }
    outp[r]     = bias + a0 + b0;
    outp[r + 1] = bias + a1 + b1;
  }
}

// ---------------------------------------------------------------------------
// Kernel 2: 16 batches/block, MFMA recurrence. grid = 8 blocks x 1024 threads.
// Wave w owns e-strip [8w,8w+8). Tile0 cols = {i,f} x strip, tile1 = {g,o}.
// Lane: c = l&15 (col), q = l>>4 (row group, b = q*4+r).
// Waves 0-3 additionally: emission MFMA (lagged 1 step) + Viterbi for b%4==w.
// ---------------------------------------------------------------------------
__global__ __launch_bounds__(1024, 4) void lstm_crf_kernel(
    const float* __restrict__ P, const float* __restrict__ Whh,
    const float* __restrict__ h0, const float* __restrict__ c0,
    const float* __restrict__ Wtag, const float* __restrict__ btag,
    const float* __restrict__ trans, float* __restrict__ out)
{
  __shared__ unsigned char bp[256 * 192];                 // 49152 B nibble-packed
  __shared__ __align__(16) unsigned short hbuf[2][2048];  // 8 KB, h bf16 dbuf
  __shared__ __align__(16) float vit[16 * 16];            // 1 KB trellis
  __shared__ __align__(16) float trl[KK * 16];            // trl[j*16+i]=trans[i][j]
  __shared__ __align__(16) bf16x8 we_lds[4 * 64];         // 4 KB Wtag B-frags

  const int bg  = blockIdx.x;       // batch group (16 batches)
  const int tid = threadIdx.x;
  const int w   = tid >> 6;         // wave 0..15
  const int l   = tid & 63;
  const int c   = l & 15;           // MFMA col
  const int q   = l >> 4;           // row group
  const bool lowc = (c < 8);
  const int e   = 8 * w + (lowc ? c : c - 8);
  const bool vw = (w < 4);          // viterbi waves
  const int j   = c;                // tag id for vw lanes

  // ---- B fragments for the gate GEMM (persistent registers) ----
  const int g0 = lowc ? (8 * w + c) : (HH + 8 * w + (c - 8));   // i / f
  const int g1 = g0 + 256;                                      // g / o
  bf16x8 wb0[4], wb1[4];
  #pragma unroll
  for (int kt = 0; kt < 4; ++kt) {
    int k0 = kt * 32 + q * 8;
    wb0[kt] = load8_bf(Whh + (size_t)g0 * HH + k0);
    wb1[kt] = load8_bf(Whh + (size_t)g1 * HH + k0);
  }

  // ---- cell state for (b=q*4+r, e), lives in c>=8 lanes ----
  float cst[4];
  #pragma unroll
  for (int r = 0; r < 4; ++r)
    cst[r] = c0[(size_t)(bg * 16 + q * 4 + r) * HH + e];

  // ---- h0 -> hbuf[0] (bf16, swizzled) ----
  for (int idx = tid; idx < 2048; idx += 1024) {
    int b = idx >> 7, k = idx & 127;
    hbuf[0][hswz(b, k)] = f2bf(h0[(size_t)(bg * 16 + b) * HH + k]);
  }
  // ---- Wtag B-frags -> LDS ----
  if (tid < 256) {
    int kt = tid >> 6, l2 = tid & 63, c2 = l2 & 15, q2 = l2 >> 4;
    bf16x8 f;
    if (c2 < KK) {
      f = load8_bf(Wtag + (size_t)c2 * HH + kt * 32 + q2 * 8);
    } else {
      for (int i = 0; i < 8; ++i) f[i] = 0;
    }
    we_lds[tid] = f;
  }
  // ---- transitions (transposed, padded) -> LDS ----
  if (tid < KK * KK) {
    int i = tid / KK, jj = tid - i * KK;
    trl[jj * 16 + i] = trans[tid];
  }
  float bt = (vw && j < KK) ? btag[j] : 0.f;

  // ---- pregate streams ----
  const float* pP0 = P + (size_t)g0 * BB + bg * 16 + q * 4;
  const float* pP1 = P + (size_t)g1 * BB + bg * 16 + q * 4;
  float4 pc0 = *reinterpret_cast<const float4*>(pP0);
  float4 pc1 = *reinterpret_cast<const float4*>(pP1);

  int nib = 0;
  __syncthreads();

  for (int s = 0; s <= TT; ++s) {
    const int rb = s & 1;

    // prefetch next step's pregates
    float4 pn0 = pc0, pn1 = pc1;
    if (s + 1 < TT) {
      pn0 = *reinterpret_cast<const float4*>(pP0 + (size_t)(s + 1) * (G4 * BB));
      pn1 = *reinterpret_cast<const float4*>(pP1 + (size_t)(s + 1) * (G4 * BB));
    }

    // A fragments: h[b][k] bf16 from swizzled LDS (row b = c)
    bf16x8 a[4];
    if (s < TT || vw) {
      const char* hb = reinterpret_cast<const char*>(hbuf[rb]);
      #pragma unroll
      for (int kt = 0; kt < 4; ++kt)
        a[kt] = *reinterpret_cast<const bf16x8*>(
            hb + c * 256 + ((kt * 64 + q * 16) ^ ((c & 7) << 4)));
    }

    // ---- emissions (lagged: uses h(s-1)) + Viterbi t = s-1, waves 0-3 ----
    if (vw && s >= 1) {
      f32x4 accE = {0.f, 0.f, 0.f, 0.f};
      #pragma unroll
      for (int kt = 0; kt < 4; ++kt) {
        bf16x8 bw = we_lds[kt * 64 + l];
        accE = __builtin_amdgcn_mfma_f32_16x16x32_bf16(a[kt], bw, accE, 0, 0, 0);
      }
      float Ev = (w == 0 ? accE[0] : w == 1 ? accE[1] : w == 2 ? accE[2] : accE[3]) + bt;
      if (j < KK) {
        int b = q * 4 + w;
        float nv;
        if (s == 1) {
          nv = Ev;                                  // t = 0 init
        } else {
          float4 v0 = *reinterpret_cast<const float4*>(&vit[b * 16]);
          float4 v1 = *reinterpret_cast<const float4*>(&vit[b * 16 + 4]);
          float4 v2 = *reinterpret_cast<const float4*>(&vit[b * 16 + 8]);
          float4 t0 = *reinterpret_cast<const float4*>(&trl[j * 16]);
          float4 t1 = *reinterpret_cast<const float4*>(&trl[j * 16 + 4]);
          float4 t2 = *reinterpret_cast<const float4*>(&trl[j * 16 + 8]);
          float cand[KK] = {v0.x + t0.x, v0.y + t0.y, v0.z + t0.z, v0.w + t0.w,
                            v1.x + t1.x, v1.y + t1.y, v1.z + t1.z, v1.w + t1.w,
                            v2.x + t2.x, v2.y + t2.y, v2.z + t2.z, v2.w + t2.w};
          float best = cand[0];
          int bi = 0;
          #pragma unroll
          for (int i = 1; i < KK; ++i)
            if (cand[i] > best) { best = cand[i]; bi = i; }   // first-max
          nv = Ev + best;
          int t_ = s - 1;
          if (t_ & 1) bp[(t_ >> 1) * 192 + b * 12 + j] =
                          (unsigned char)(nib | (bi << 4));
          else        nib = bi;
        }
        vit[b * 16 + j] = nv;
      }
    }

    // ---- gate GEMM + cell update ----
    if (s < TT) {
      f32x4 acc0 = {0.f, 0.f, 0.f, 0.f}, acc1 = {0.f, 0.f, 0.f, 0.f};
      #pragma unroll
      for (int kt = 0; kt < 4; ++kt) {
        acc0 = __builtin_amdgcn_mfma_f32_16x16x32_bf16(a[kt], wb0[kt], acc0, 0, 0, 0);
        acc1 = __builtin_amdgcn_mfma_f32_16x16x32_bf16(a[kt], wb1[kt], acc1, 0, 0, 0);
      }
      float A_[4], B_[4], u[4];
      #pragma unroll
      for (int r = 0; r < 4; ++r) {
        A_[r] = fsig(acc0[r] + pc0[r]);                 // sig(i) or sig(f)
        float x1 = acc1[r] + pc1[r];
        float y  = fsig(lowc ? x1 + x1 : x1);
        B_[r] = lowc ? (y + y - 1.0f) : y;              // tanh(g) or sig(o)
        u[r]  = A_[r] * B_[r];                          // sig(i)*tanh(g) on lowc
      }
      #pragma unroll
      for (int r = 0; r < 4; ++r) u[r] = __shfl_xor(u[r], 8);
      if (!lowc) {
        unsigned short* hw = hbuf[rb ^ 1];
        #pragma unroll
        for (int r = 0; r < 4; ++r) {
          cst[r] = __fmaf_rn(A_[r], cst[r], u[r]);      // sig(f)*c + u
          float yc = fsig(cst[r] + cst[r]);
          float hv = B_[r] * (yc + yc - 1.0f);          // sig(o)*tanh(c)
          hw[hswz(q * 4 + r, e)] = f2bf(hv);
        }
      }
      pc0 = pn0; pc1 = pn1;
    }
    __syncthreads();
  }

  // ---- scores + backtrace (16 parallel chains, one per batch) ----
  unsigned char* pb = reinterpret_cast<unsigned char*>(hbuf);  // reuse 8 KB
  if (tid < 16) {
    int b = tid;
    float best = vit[b * 16];
    int tag = 0;
    for (int jj = 1; jj < KK; ++jj) {
      float v = vit[b * 16 + jj];
      if (v > best) { best = v; tag = jj; }
    }
    out[bg * 16 + b] = best;                    // scores
    pb[b * 512 + 511] = (unsigned char)tag;
    for (int t_ = TT - 1; t_ >= 1; --t_) {
      unsigned char byte = bp[(t_ >> 1) * 192 + b * 12 + tag];
      tag = (t_ & 1) ? (byte >> 4) & 15 : (byte & 15);
      pb[b * 512 + t_ - 1] = (unsigned char)tag;
    }
  }
  __syncthreads();

  #pragma unroll
  for (int i = 0; i < 8; ++i) {
    int idx = tid + i * 1024;
    out[BB + (size_t)bg * 8192 + idx] = (float)pb[idx];
  }
}

// ---------------------------------------------------------------------------
extern "C" void kernel_launch(void* const* d_in, const int* in_sizes, int n_in,
                              void* d_out, int out_size, void* d_ws, size_t ws_size,
                              hipStream_t stream) {
  const int*   sent  = (const int*)d_in[0];
  const float* h0    = (const float*)d_in[1];
  const float* c0    = (const float*)d_in[2];
  const float* embed = (const float*)d_in[3];
  const float* Wih   = (const float*)d_in[4];
  const float* Whh   = (const float*)d_in[5];
  const float* bih   = (const float*)d_in[6];
  const float* bhh   = (const float*)d_in[7];
  const float* Wtag  = (const float*)d_in[8];
  const float* btag  = (const float*)d_in[9];
  const float* trans = (const float*)d_in[10];
  float* out = (float*)d_out;
  float* P   = (float*)d_ws;   // [T][4H][B] fp32 = 128 MB

  pregates_kernel<<<TT, 512, 0, stream>>>(sent, embed, Wih, bih, bhh, P);
  lstm_crf_kernel<<<BB / 16, 1024, 0, stream>>>(P, Whh, h0, c0, Wtag, btag, trans, out);
}

// Round 5
// 1590.900 us; speedup vs baseline: 1.1722x; 1.1722x over previous
//
#include <hip/hip_runtime.h>
#include <hip/hip_bf16.h>

#define BB 128   // batch
#define TT 512   // time
#define EE 100   // embed dim
#define HH 128   // hidden
#define G4 512   // 4*H
#define KK 12    // tags

typedef short bf16x8 __attribute__((ext_vector_type(8)));
typedef float f32x4  __attribute__((ext_vector_type(4)));

__device__ __forceinline__ unsigned short f2bf(float x) {
  __hip_bfloat16 h = __float2bfloat16(x);
  return *reinterpret_cast<unsigned short*>(&h);
}

__device__ __forceinline__ bf16x8 load8_bf(const float* p) {
  float4 a = *reinterpret_cast<const float4*>(p);
  float4 b = *reinterpret_cast<const float4*>(p + 4);
  bf16x8 r;
  r[0] = (short)f2bf(a.x); r[1] = (short)f2bf(a.y);
  r[2] = (short)f2bf(a.z); r[3] = (short)f2bf(a.w);
  r[4] = (short)f2bf(b.x); r[5] = (short)f2bf(b.y);
  r[6] = (short)f2bf(b.z); r[7] = (short)f2bf(b.w);
  return r;
}

// scalar loads with zero-padding past n (for the E=100 -> K=128 pad)
__device__ __forceinline__ bf16x8 load8_bf_pad(const float* row, int k0, int n) {
  bf16x8 r;
  #pragma unroll
  for (int i = 0; i < 8; ++i) {
    unsigned short v = 0;
    if (k0 + i < n) v = f2bf(row[k0 + i]);
    r[i] = (short)v;
  }
  return r;
}

__device__ __forceinline__ float fsig(float x) {
  return 1.0f / (1.0f + __expf(-x));
}

// swizzled ushort index for tile[b][k] bf16: byte = b*256 + ((k*2) ^ ((b&7)<<4))
__device__ __forceinline__ int hswz(int b, int k) {
  return b * 128 + ((((k * 2) ^ ((b & 7) << 4))) >> 1);
}

// ---------------------------------------------------------------------------
// Fused kernel: embed-gather + input projection + LSTM + emissions + Viterbi
// + backtrace. grid = 8 blocks (16 batches each) x 1024 threads (16 waves).
// Wave w owns gate-column strip; waves 0-3 also run emissions/Viterbi
// (lagged one step); waves 8-15 also stage x(t) tiles (2-step pipeline).
// ---------------------------------------------------------------------------
__global__ __launch_bounds__(1024, 4) void lstm_crf_fused(
    const int* __restrict__ sent, const float* __restrict__ embed,
    const float* __restrict__ Wih, const float* __restrict__ Whh,
    const float* __restrict__ bih, const float* __restrict__ bhh,
    const float* __restrict__ h0, const float* __restrict__ c0,
    const float* __restrict__ Wtag, const float* __restrict__ btag,
    const float* __restrict__ trans, float* __restrict__ out)
{
  __shared__ unsigned char bp[256 * 192];                 // 48 KB nibble-packed
  __shared__ __align__(16) unsigned short hbuf[2][2048];  // 8 KB h bf16 dbuf
  __shared__ __align__(16) unsigned short xbuf[2][2048];  // 8 KB x bf16 dbuf
  __shared__ __align__(16) float vit[16 * 16];            // 1 KB trellis
  __shared__ __align__(16) float trl[KK * 16];            // trl[j*16+i]=trans[i][j]
  __shared__ __align__(16) bf16x8 we_lds[4 * 64];         // 4 KB Wtag B-frags

  const int bg  = blockIdx.x;
  const int tid = threadIdx.x;
  const int w   = tid >> 6;         // wave 0..15
  const int l   = tid & 63;
  const int c   = l & 15;           // MFMA col
  const int q   = l >> 4;           // row group (b = q*4+r)
  const bool lowc = (c < 8);
  const int e   = 8 * w + (lowc ? c : c - 8);
  const bool vw = (w < 4);          // viterbi waves
  const int j   = c;                // tag id for vw lanes

  // ---- B fragments: gate columns g0 (i/f) and g1 (g/o), for Whh and Wih ----
  const int g0 = lowc ? (8 * w + c) : (HH + 8 * w + (c - 8));
  const int g1 = g0 + 256;
  bf16x8 wh0[4], wh1[4], wx0[4], wx1[4];
  #pragma unroll
  for (int kt = 0; kt < 4; ++kt) {
    int k0 = kt * 32 + q * 8;
    wh0[kt] = load8_bf(Whh + (size_t)g0 * HH + k0);
    wh1[kt] = load8_bf(Whh + (size_t)g1 * HH + k0);
    wx0[kt] = load8_bf_pad(Wih + (size_t)g0 * EE, k0, EE);
    wx1[kt] = load8_bf_pad(Wih + (size_t)g1 * EE, k0, EE);
  }
  const float bias0 = bih[g0] + bhh[g0];
  const float bias1 = bih[g1] + bhh[g1];

  // ---- cell state for (b=q*4+r, e) ----
  float cst[4];
  #pragma unroll
  for (int r = 0; r < 4; ++r)
    cst[r] = c0[(size_t)(bg * 16 + q * 4 + r) * HH + e];

  // ---- h0 -> hbuf[0] (bf16, swizzled) ----
  for (int idx = tid; idx < 2048; idx += 1024) {
    int b = idx >> 7, k = idx & 127;
    hbuf[0][hswz(b, k)] = f2bf(h0[(size_t)(bg * 16 + b) * HH + k]);
  }
  // ---- Wtag B-frags -> LDS ----
  if (tid < 256) {
    int kt = tid >> 6, l2 = tid & 63, c2 = l2 & 15, q2 = l2 >> 4;
    bf16x8 f;
    if (c2 < KK) {
      f = load8_bf(Wtag + (size_t)c2 * HH + kt * 32 + q2 * 8);
    } else {
      for (int i = 0; i < 8; ++i) f[i] = 0;
    }
    we_lds[tid] = f;
  }
  // ---- transitions (transposed, padded) -> LDS ----
  if (tid < KK * KK) {
    int i = tid / KK, jj = tid - i * KK;
    trl[jj * 16 + i] = trans[tid];
  }
  float bt = (vw && j < KK) ? btag[j] : 0.f;

  // ---- x staging (waves 8-15): sb = batch row, kq = float4 index (25 valid) ----
  const bool stg  = (tid >= 512);
  const int  sb   = (tid >> 5) & 15;
  const int  kq   = tid & 31;
  const bool stga = stg && (kq < 25);
  const int* sentb = sent + (size_t)(bg * 16 + sb) * TT;

  if (stg && kq >= 25) {   // zero tails k in [100,128) of both buffers, once
    short4 z = make_short4(0, 0, 0, 0);
    *reinterpret_cast<short4*>(
        reinterpret_cast<char*>(xbuf[0]) + sb * 256 + ((kq * 8) ^ ((sb & 7) << 4))) = z;
    *reinterpret_cast<short4*>(
        reinterpret_cast<char*>(xbuf[1]) + sb * 256 + ((kq * 8) ^ ((sb & 7) << 4))) = z;
  }
  if (stga) {              // stage x(0) directly
    const float* er = embed + (size_t)sentb[0] * EE;
    float4 v = *reinterpret_cast<const float4*>(er + kq * 4);
    short4 pk = make_short4((short)f2bf(v.x), (short)f2bf(v.y),
                            (short)f2bf(v.z), (short)f2bf(v.w));
    *reinterpret_cast<short4*>(
        reinterpret_cast<char*>(xbuf[0]) + sb * 256 + ((kq * 8) ^ ((sb & 7) << 4))) = pk;
  }
  float4 xv = {0.f, 0.f, 0.f, 0.f};
  if (stga) {              // issue loads for x(1)
    const float* er = embed + (size_t)sentb[1] * EE;
    xv = *reinterpret_cast<const float4*>(er + kq * 4);
  }

  int nib = 0;
  __syncthreads();

  for (int s = 0; s <= TT; ++s) {
    const int rb = s & 1;

    // A fragments: h(s-1)-tile (always), shared by emission + gate GEMM
    bf16x8 ha[4];
    const char* hb = reinterpret_cast<const char*>(hbuf[rb]);
    #pragma unroll
    for (int kt = 0; kt < 4; ++kt)
      ha[kt] = *reinterpret_cast<const bf16x8*>(
          hb + c * 256 + ((kt * 64 + q * 16) ^ ((c & 7) << 4)));

    // ---- emissions (h after step s-1) + Viterbi t = s-1, waves 0-3 ----
    if (vw && s >= 1) {
      f32x4 accE = {0.f, 0.f, 0.f, 0.f};
      #pragma unroll
      for (int kt = 0; kt < 4; ++kt) {
        bf16x8 bw = we_lds[kt * 64 + l];
        accE = __builtin_amdgcn_mfma_f32_16x16x32_bf16(ha[kt], bw, accE, 0, 0, 0);
      }
      float Ev = (w == 0 ? accE[0] : w == 1 ? accE[1] : w == 2 ? accE[2] : accE[3]) + bt;
      if (j < KK) {
        int b = q * 4 + w;
        float nv;
        if (s == 1) {
          nv = Ev;
        } else {
          float4 v0 = *reinterpret_cast<const float4*>(&vit[b * 16]);
          float4 v1 = *reinterpret_cast<const float4*>(&vit[b * 16 + 4]);
          float4 v2 = *reinterpret_cast<const float4*>(&vit[b * 16 + 8]);
          float4 t0 = *reinterpret_cast<const float4*>(&trl[j * 16]);
          float4 t1 = *reinterpret_cast<const float4*>(&trl[j * 16 + 4]);
          float4 t2 = *reinterpret_cast<const float4*>(&trl[j * 16 + 8]);
          float cand[KK] = {v0.x + t0.x, v0.y + t0.y, v0.z + t0.z, v0.w + t0.w,
                            v1.x + t1.x, v1.y + t1.y, v1.z + t1.z, v1.w + t1.w,
                            v2.x + t2.x, v2.y + t2.y, v2.z + t2.z, v2.w + t2.w};
          float best = cand[0];
          int bi = 0;
          #pragma unroll
          for (int i = 1; i < KK; ++i)
            if (cand[i] > best) { best = cand[i]; bi = i; }   // first-max
          nv = Ev + best;
          int t_ = s - 1;
          if (t_ & 1) bp[(t_ >> 1) * 192 + b * 12 + j] =
                          (unsigned char)(nib | (bi << 4));
          else        nib = bi;
        }
        vit[b * 16 + j] = nv;
      }
    }

    if (s < TT) {
      // x(s)-tile A fragments
      bf16x8 xa[4];
      const char* xb = reinterpret_cast<const char*>(xbuf[rb]);
      #pragma unroll
      for (int kt = 0; kt < 4; ++kt)
        xa[kt] = *reinterpret_cast<const bf16x8*>(
            xb + c * 256 + ((kt * 64 + q * 16) ^ ((c & 7) << 4)));

      // write staged x(s+1); issue loads for x(s+2)
      if (stga && s + 1 < TT) {
        short4 pk = make_short4((short)f2bf(xv.x), (short)f2bf(xv.y),
                                (short)f2bf(xv.z), (short)f2bf(xv.w));
        *reinterpret_cast<short4*>(
            reinterpret_cast<char*>(xbuf[rb ^ 1]) + sb * 256 +
            ((kq * 8) ^ ((sb & 7) << 4))) = pk;
      }
      if (stga && s + 2 < TT) {
        const float* er = embed + (size_t)sentb[s + 2] * EE;
        xv = *reinterpret_cast<const float4*>(er + kq * 4);
      }

      // ---- gate GEMM: bias + x@Wih^T + h@Whh^T ----
      f32x4 acc0 = {bias0, bias0, bias0, bias0};
      f32x4 acc1 = {bias1, bias1, bias1, bias1};
      #pragma unroll
      for (int kt = 0; kt < 4; ++kt) {
        acc0 = __builtin_amdgcn_mfma_f32_16x16x32_bf16(xa[kt], wx0[kt], acc0, 0, 0, 0);
        acc1 = __builtin_amdgcn_mfma_f32_16x16x32_bf16(xa[kt], wx1[kt], acc1, 0, 0, 0);
      }
      #pragma unroll
      for (int kt = 0; kt < 4; ++kt) {
        acc0 = __builtin_amdgcn_mfma_f32_16x16x32_bf16(ha[kt], wh0[kt], acc0, 0, 0, 0);
        acc1 = __builtin_amdgcn_mfma_f32_16x16x32_bf16(ha[kt], wh1[kt], acc1, 0, 0, 0);
      }

      // ---- cell update (lane pairs c <-> c^8), h write-back ----
      float A_[4], B_[4], u[4];
      #pragma unroll
      for (int r = 0; r < 4; ++r) {
        A_[r] = fsig(acc0[r]);                          // sig(i) or sig(f)
        float x1 = acc1[r];
        float y  = fsig(lowc ? x1 + x1 : x1);
        B_[r] = lowc ? (y + y - 1.0f) : y;              // tanh(g) or sig(o)
        u[r]  = A_[r] * B_[r];                          // sig(i)*tanh(g) on lowc
      }
      #pragma unroll
      for (int r = 0; r < 4; ++r) u[r] = __shfl_xor(u[r], 8);
      if (!lowc) {
        unsigned short* hw = hbuf[rb ^ 1];
        #pragma unroll
        for (int r = 0; r < 4; ++r) {
          cst[r] = __fmaf_rn(A_[r], cst[r], u[r]);      // sig(f)*c + sig(i)*tanh(g)
          float yc = fsig(cst[r] + cst[r]);
          float hv = B_[r] * (yc + yc - 1.0f);          // sig(o)*tanh(c)
          hw[hswz(q * 4 + r, e)] = f2bf(hv);
        }
      }
    }
    __syncthreads();
  }

  // ---- scores + backtrace (16 parallel chains) ----
  unsigned char* pb = reinterpret_cast<unsigned char*>(hbuf);  // reuse 8 KB
  if (tid < 16) {
    int b = tid;
    float best = vit[b * 16];
    int tag = 0;
    for (int jj = 1; jj < KK; ++jj) {
      float v = vit[b * 16 + jj];
      if (v > best) { best = v; tag = jj; }
    }
    out[bg * 16 + b] = best;                    // scores
    pb[b * 512 + 511] = (unsigned char)tag;
    for (int t_ = TT - 1; t_ >= 1; --t_) {
      unsigned char byte = bp[(t_ >> 1) * 192 + b * 12 + tag];
      tag = (t_ & 1) ? (byte >> 4) & 15 : (byte & 15);
      pb[b * 512 + t_ - 1] = (unsigned char)tag;
    }
  }
  __syncthreads();

  #pragma unroll
  for (int i = 0; i < 8; ++i) {
    int idx = tid + i * 1024;
    out[BB + (size_t)bg * 8192 + idx] = (float)pb[idx];
  }
}

// ---------------------------------------------------------------------------
extern "C" void kernel_launch(void* const* d_in, const int* in_sizes, int n_in,
                              void* d_out, int out_size, void* d_ws, size_t ws_size,
                              hipStream_t stream) {
  const int*   sent  = (const int*)d_in[0];
  const float* h0    = (const float*)d_in[1];
  const float* c0    = (const float*)d_in[2];
  const float* embed = (const float*)d_in[3];
  const float* Wih   = (const float*)d_in[4];
  const float* Whh   = (const float*)d_in[5];
  const float* bih   = (const float*)d_in[6];
  const float* bhh   = (const float*)d_in[7];
  const float* Wtag  = (const float*)d_in[8];
  const float* btag  = (const float*)d_in[9];
  const float* trans = (const float*)d_in[10];
  float* out = (float*)d_out;

  lstm_crf_fused<<<BB / 16, 1024, 0, stream>>>(
      sent, embed, Wih, Whh, bih, bhh, h0, c0, Wtag, btag, trans, out);
}

// Round 6
// 1327.949 us; speedup vs baseline: 1.4043x; 1.1980x over previous
//
#include <hip/hip_runtime.h>
#include <hip/hip_bf16.h>

#define BB 128   // batch
#define TT 512   // time
#define EE 100   // embed dim
#define HH 128   // hidden
#define KK 12    // tags

typedef short bf16x8 __attribute__((ext_vector_type(8)));
typedef float f32x4  __attribute__((ext_vector_type(4)));

__device__ __forceinline__ unsigned short f2bf(float x) {
  __hip_bfloat16 h = __float2bfloat16(x);
  return *reinterpret_cast<unsigned short*>(&h);
}

__device__ __forceinline__ bf16x8 load8_bf(const float* p) {
  float4 a = *reinterpret_cast<const float4*>(p);
  float4 b = *reinterpret_cast<const float4*>(p + 4);
  bf16x8 r;
  r[0] = (short)f2bf(a.x); r[1] = (short)f2bf(a.y);
  r[2] = (short)f2bf(a.z); r[3] = (short)f2bf(a.w);
  r[4] = (short)f2bf(b.x); r[5] = (short)f2bf(b.y);
  r[6] = (short)f2bf(b.z); r[7] = (short)f2bf(b.w);
  return r;
}

// scalar loads with zero-padding past n (E=100 -> K=128 pad)
__device__ __forceinline__ bf16x8 load8_bf_pad(const float* row, int k0, int n) {
  bf16x8 r;
  #pragma unroll
  for (int i = 0; i < 8; ++i) {
    unsigned short v = 0;
    if (k0 + i < n) v = f2bf(row[k0 + i]);
    r[i] = (short)v;
  }
  return r;
}

__device__ __forceinline__ short4 pack4(float4 v) {
  return make_short4((short)f2bf(v.x), (short)f2bf(v.y),
                     (short)f2bf(v.z), (short)f2bf(v.w));
}

__device__ __forceinline__ float fsig(float x) {
  return 1.0f / (1.0f + __expf(-x));
}

// swizzled ushort index for tile[b][k] bf16: byte = b*256 + ((k*2) ^ ((b&7)<<4))
__device__ __forceinline__ int hswz(int b, int k) {
  return b * 128 + ((((k * 2) ^ ((b & 7) << 4))) >> 1);
}

// ---------------------------------------------------------------------------
// Fused kernel. grid = 8 blocks (16 batches each) x 512 threads (8 waves).
// Wave w owns 64 gate columns: strips eA=[16w,16w+8), eB=[16w+8,16w+16),
// tiles {i|f, g|o} per strip. Waves 0-3: emissions+Viterbi (lagged 1 step).
// Waves 4-7: x(t) tile staging (2-step pipeline). One barrier per step.
// ---------------------------------------------------------------------------
__global__ __launch_bounds__(512, 2) void lstm_crf_fused(
    const int* __restrict__ sent, const float* __restrict__ embed,
    const float* __restrict__ Wih, const float* __restrict__ Whh,
    const float* __restrict__ bih, const float* __restrict__ bhh,
    const float* __restrict__ h0, const float* __restrict__ c0,
    const float* __restrict__ Wtag, const float* __restrict__ btag,
    const float* __restrict__ trans, float* __restrict__ out)
{
  __shared__ unsigned char bp[256 * 192];                 // 48 KB nibble-packed
  __shared__ __align__(16) unsigned short hbuf[2][2048];  // 8 KB h bf16 dbuf
  __shared__ __align__(16) unsigned short xbuf[2][2048];  // 8 KB x bf16 dbuf
  __shared__ __align__(16) float vit[16 * 16];            // 1 KB trellis
  __shared__ __align__(16) float trl[KK * 16];            // trl[j*16+i]=trans[i][j]

  const int bg  = blockIdx.x;
  const int tid = threadIdx.x;
  const int w   = tid >> 6;         // wave 0..7
  const int l   = tid & 63;
  const int c   = l & 15;           // MFMA col within tile
  const int q   = l >> 4;           // row group (b = q*4+r)
  const bool lowc = (c < 8);
  const int ce  = lowc ? c : c - 8;
  const bool vw = (w < 4);          // viterbi waves

  // ---- gate columns for this wave's 4 tiles ----
  // tile 0: i|f strip A; tile 1: g|o strip A; tile 2: i|f strip B; tile 3: g|o B
  const int gb = (lowc ? 0 : 128) + 16 * w + ce;
  const int gcol[4] = {gb, gb + 256, gb + 8, gb + 264};

  bf16x8 wh[4][4], wx[4][4];
  float biasv[4];
  #pragma unroll
  for (int tt = 0; tt < 4; ++tt) {
    biasv[tt] = bih[gcol[tt]] + bhh[gcol[tt]];
    #pragma unroll
    for (int kt = 0; kt < 4; ++kt) {
      const int k0 = kt * 32 + q * 8;
      wh[tt][kt] = load8_bf(Whh + (size_t)gcol[tt] * HH + k0);
      wx[tt][kt] = load8_bf_pad(Wih + (size_t)gcol[tt] * EE, k0, EE);
    }
  }

  const int eA = 16 * w + ce, eB = eA + 8;
  float cstA[4], cstB[4];
  #pragma unroll
  for (int r = 0; r < 4; ++r) {
    cstA[r] = c0[(size_t)(bg * 16 + q * 4 + r) * HH + eA];
    cstB[r] = c0[(size_t)(bg * 16 + q * 4 + r) * HH + eB];
  }

  // ---- emission weight fragments (registers, waves 0-3, tag col = c) ----
  bf16x8 we[4];
  #pragma unroll
  for (int kt = 0; kt < 4; ++kt) {
    #pragma unroll
    for (int i = 0; i < 8; ++i) we[kt][i] = 0;
  }
  float bt = 0.f;
  if (vw && c < KK) {
    #pragma unroll
    for (int kt = 0; kt < 4; ++kt)
      we[kt] = load8_bf(Wtag + (size_t)c * HH + kt * 32 + q * 8);
    bt = btag[c];
  }

  // ---- h0 -> hbuf[0] (bf16, swizzled) ----
  for (int idx = tid; idx < 2048; idx += 512) {
    int b = idx >> 7, k = idx & 127;
    hbuf[0][hswz(b, k)] = f2bf(h0[(size_t)(bg * 16 + b) * HH + k]);
  }
  // ---- transitions (transposed, padded) -> LDS ----
  if (tid < KK * KK) {
    int i = tid / KK, jj = tid - i * KK;
    trl[jj * 16 + i] = trans[tid];
  }

  // ---- x staging (waves 4-7): 256 lanes, row sb, float4 cols kq0 / kq0+16 ----
  const bool stg = (w >= 4);
  const int sid = tid & 255;
  const int sb = sid >> 4, kq0 = sid & 15;
  const bool has2 = (kq0 < 9);          // kq0+16 < 25
  const int* sentb = sent + (size_t)(bg * 16 + sb) * TT;
  char* xb0 = reinterpret_cast<char*>(xbuf[0]);
  char* xb1 = reinterpret_cast<char*>(xbuf[1]);
  if (stg) {
    if (kq0 >= 9) {                     // zero tails kq in [25,32), both bufs
      int kqz = kq0 + 16;
      short4 z = make_short4(0, 0, 0, 0);
      *reinterpret_cast<short4*>(xb0 + sb * 256 + ((kqz * 8) ^ ((sb & 7) << 4))) = z;
      *reinterpret_cast<short4*>(xb1 + sb * 256 + ((kqz * 8) ^ ((sb & 7) << 4))) = z;
    }
    const float* er = embed + (size_t)sentb[0] * EE;     // x(0) direct
    float4 v0 = *reinterpret_cast<const float4*>(er + kq0 * 4);
    *reinterpret_cast<short4*>(xb0 + sb * 256 + ((kq0 * 8) ^ ((sb & 7) << 4))) = pack4(v0);
    if (has2) {
      float4 v1 = *reinterpret_cast<const float4*>(er + (kq0 + 16) * 4);
      *reinterpret_cast<short4*>(xb0 + sb * 256 + (((kq0 + 16) * 8) ^ ((sb & 7) << 4))) = pack4(v1);
    }
  }
  float4 xv0 = {0.f, 0.f, 0.f, 0.f}, xv1 = {0.f, 0.f, 0.f, 0.f};
  if (stg) {                            // issue loads for x(1)
    const float* er = embed + (size_t)sentb[1] * EE;
    xv0 = *reinterpret_cast<const float4*>(er + kq0 * 4);
    if (has2) xv1 = *reinterpret_cast<const float4*>(er + (kq0 + 16) * 4);
  }

  int nib = 0;
  __syncthreads();

  for (int s = 0; s <= TT; ++s) {
    const int rb = s & 1;

    // A fragments: h(s-1)-tile, shared by emission + gate GEMM
    bf16x8 ha[4];
    const char* hb = reinterpret_cast<const char*>(hbuf[rb]);
    #pragma unroll
    for (int kt = 0; kt < 4; ++kt)
      ha[kt] = *reinterpret_cast<const bf16x8*>(
          hb + c * 256 + ((kt * 64 + q * 16) ^ ((c & 7) << 4)));

    // ---- emissions (h after step s-1) + Viterbi t = s-1, waves 0-3 ----
    if (vw && s >= 1) {
      f32x4 accE = {0.f, 0.f, 0.f, 0.f};
      #pragma unroll
      for (int kt = 0; kt < 4; ++kt)
        accE = __builtin_amdgcn_mfma_f32_16x16x32_bf16(ha[kt], we[kt], accE, 0, 0, 0);
      float Ev = (w == 0 ? accE[0] : w == 1 ? accE[1] : w == 2 ? accE[2] : accE[3]) + bt;
      if (c < KK) {
        const int b = q * 4 + w;
        const int j = c;
        float nv;
        if (s == 1) {
          nv = Ev;
        } else {
          float4 v0 = *reinterpret_cast<const float4*>(&vit[b * 16]);
          float4 v1 = *reinterpret_cast<const float4*>(&vit[b * 16 + 4]);
          float4 v2 = *reinterpret_cast<const float4*>(&vit[b * 16 + 8]);
          float4 t0 = *reinterpret_cast<const float4*>(&trl[j * 16]);
          float4 t1 = *reinterpret_cast<const float4*>(&trl[j * 16 + 4]);
          float4 t2 = *reinterpret_cast<const float4*>(&trl[j * 16 + 8]);
          float cand[KK] = {v0.x + t0.x, v0.y + t0.y, v0.z + t0.z, v0.w + t0.w,
                            v1.x + t1.x, v1.y + t1.y, v1.z + t1.z, v1.w + t1.w,
                            v2.x + t2.x, v2.y + t2.y, v2.z + t2.z, v2.w + t2.w};
          float best = cand[0];
          int bi = 0;
          #pragma unroll
          for (int i = 1; i < KK; ++i)
            if (cand[i] > best) { best = cand[i]; bi = i; }   // first-max
          nv = Ev + best;
          const int t_ = s - 1;
          if (t_ & 1) bp[(t_ >> 1) * 192 + b * 12 + j] =
                          (unsigned char)(nib | (bi << 4));
          else        nib = bi;
        }
        vit[b * 16 + j] = nv;
      }
    }

    if (s < TT) {
      // x(s)-tile A fragments
      bf16x8 xa[4];
      const char* xb = reinterpret_cast<const char*>(xbuf[rb]);
      #pragma unroll
      for (int kt = 0; kt < 4; ++kt)
        xa[kt] = *reinterpret_cast<const bf16x8*>(
            xb + c * 256 + ((kt * 64 + q * 16) ^ ((c & 7) << 4)));

      // staging: write x(s+1), then issue loads for x(s+2)
      if (stg && s + 1 < TT) {
        char* xw = reinterpret_cast<char*>(xbuf[rb ^ 1]);
        *reinterpret_cast<short4*>(xw + sb * 256 + ((kq0 * 8) ^ ((sb & 7) << 4))) = pack4(xv0);
        if (has2)
          *reinterpret_cast<short4*>(xw + sb * 256 + (((kq0 + 16) * 8) ^ ((sb & 7) << 4))) = pack4(xv1);
      }
      if (stg && s + 2 < TT) {
        const float* er = embed + (size_t)sentb[s + 2] * EE;
        xv0 = *reinterpret_cast<const float4*>(er + kq0 * 4);
        if (has2) xv1 = *reinterpret_cast<const float4*>(er + (kq0 + 16) * 4);
      }

      // ---- gate GEMM: bias + x@Wih^T + h@Whh^T, 4 tiles ----
      f32x4 acc[4];
      #pragma unroll
      for (int tt = 0; tt < 4; ++tt) {
        acc[tt][0] = biasv[tt]; acc[tt][1] = biasv[tt];
        acc[tt][2] = biasv[tt]; acc[tt][3] = biasv[tt];
      }
      #pragma unroll
      for (int kt = 0; kt < 4; ++kt) {
        #pragma unroll
        for (int tt = 0; tt < 4; ++tt)
          acc[tt] = __builtin_amdgcn_mfma_f32_16x16x32_bf16(xa[kt], wx[tt][kt], acc[tt], 0, 0, 0);
      }
      #pragma unroll
      for (int kt = 0; kt < 4; ++kt) {
        #pragma unroll
        for (int tt = 0; tt < 4; ++tt)
          acc[tt] = __builtin_amdgcn_mfma_f32_16x16x32_bf16(ha[kt], wh[tt][kt], acc[tt], 0, 0, 0);
      }

      // ---- cell update (lane pairs c <-> c^8), strips A and B ----
      unsigned short* hw = hbuf[rb ^ 1];
      {
        float A_[4], B_[4], u[4];
        #pragma unroll
        for (int r = 0; r < 4; ++r) {
          A_[r] = fsig(acc[0][r]);                        // sig(i) | sig(f)
          float x1 = acc[1][r];
          float y  = fsig(lowc ? x1 + x1 : x1);
          B_[r] = lowc ? (y + y - 1.0f) : y;              // tanh(g) | sig(o)
          u[r]  = A_[r] * B_[r];
        }
        #pragma unroll
        for (int r = 0; r < 4; ++r) u[r] = __shfl_xor(u[r], 8);
        if (!lowc) {
          #pragma unroll
          for (int r = 0; r < 4; ++r) {
            cstA[r] = __fmaf_rn(A_[r], cstA[r], u[r]);
            float yc = fsig(cstA[r] + cstA[r]);
            hw[hswz(q * 4 + r, eA)] = f2bf(B_[r] * (yc + yc - 1.0f));
          }
        }
      }
      {
        float A_[4], B_[4], u[4];
        #pragma unroll
        for (int r = 0; r < 4; ++r) {
          A_[r] = fsig(acc[2][r]);
          float x1 = acc[3][r];
          float y  = fsig(lowc ? x1 + x1 : x1);
          B_[r] = lowc ? (y + y - 1.0f) : y;
          u[r]  = A_[r] * B_[r];
        }
        #pragma unroll
        for (int r = 0; r < 4; ++r) u[r] = __shfl_xor(u[r], 8);
        if (!lowc) {
          #pragma unroll
          for (int r = 0; r < 4; ++r) {
            cstB[r] = __fmaf_rn(A_[r], cstB[r], u[r]);
            float yc = fsig(cstB[r] + cstB[r]);
            hw[hswz(q * 4 + r, eB)] = f2bf(B_[r] * (yc + yc - 1.0f));
          }
        }
      }
    }
    __syncthreads();
  }

  // ---- scores + backtrace (16 parallel chains) ----
  unsigned char* pb = reinterpret_cast<unsigned char*>(hbuf);  // reuse 8 KB
  if (tid < 16) {
    int b = tid;
    float best = vit[b * 16];
    int tag = 0;
    for (int jj = 1; jj < KK; ++jj) {
      float v = vit[b * 16 + jj];
      if (v > best) { best = v; tag = jj; }
    }
    out[bg * 16 + b] = best;                    // scores
    pb[b * 512 + 511] = (unsigned char)tag;
    for (int t_ = TT - 1; t_ >= 1; --t_) {
      unsigned char byte = bp[(t_ >> 1) * 192 + b * 12 + tag];
      tag = (t_ & 1) ? (byte >> 4) & 15 : (byte & 15);
      pb[b * 512 + t_ - 1] = (unsigned char)tag;
    }
  }
  __syncthreads();

  #pragma unroll
  for (int i = 0; i < 16; ++i) {
    int idx = tid + i * 512;
    out[BB + (size_t)bg * 8192 + idx] = (float)pb[idx];
  }
}

// ---------------------------------------------------------------------------
extern "C" void kernel_launch(void* const* d_in, const int* in_sizes, int n_in,
                              void* d_out, int out_size, void* d_ws, size_t ws_size,
                              hipStream_t stream) {
  const int*   sent  = (const int*)d_in[0];
  const float* h0    = (const float*)d_in[1];
  const float* c0    = (const float*)d_in[2];
  const float* embed = (const float*)d_in[3];
  const float* Wih   = (const float*)d_in[4];
  const float* Whh   = (const float*)d_in[5];
  const float* bih   = (const float*)d_in[6];
  const float* bhh   = (const float*)d_in[7];
  const float* Wtag  = (const float*)d_in[8];
  const float* btag  = (const float*)d_in[9];
  const float* trans = (const float*)d_in[10];
  float* out = (float*)d_out;

  lstm_crf_fused<<<BB / 16, 512, 0, stream>>>(
      sent, embed, Wih, Whh, bih, bhh, h0, c0, Wtag, btag, trans, out);
}

// Round 7
// 725.059 us; speedup vs baseline: 2.5721x; 1.8315x over previous
//
#include <hip/hip_runtime.h>
#include <hip/hip_bf16.h>

#define BB 128   // batch
#define TT 512   // time
#define EE 100   // embed dim
#define HH 128   // hidden
#define KK 12    // tags

typedef short bf16x8 __attribute__((ext_vector_type(8)));
typedef float f32x4  __attribute__((ext_vector_type(4)));

__device__ __forceinline__ unsigned short f2bf(float x) {
  __hip_bfloat16 h = __float2bfloat16(x);
  return *reinterpret_cast<unsigned short*>(&h);
}

__device__ __forceinline__ bf16x8 load8_bf(const float* p) {
  float4 a = *reinterpret_cast<const float4*>(p);
  float4 b = *reinterpret_cast<const float4*>(p + 4);
  bf16x8 r;
  r[0] = (short)f2bf(a.x); r[1] = (short)f2bf(a.y);
  r[2] = (short)f2bf(a.z); r[3] = (short)f2bf(a.w);
  r[4] = (short)f2bf(b.x); r[5] = (short)f2bf(b.y);
  r[6] = (short)f2bf(b.z); r[7] = (short)f2bf(b.w);
  return r;
}

// scalar loads with zero-padding past n (E=100 -> K=128 pad)
__device__ __forceinline__ bf16x8 load8_bf_pad(const float* row, int k0, int n) {
  bf16x8 r;
  #pragma unroll
  for (int i = 0; i < 8; ++i) {
    unsigned short v = 0;
    if (k0 + i < n) v = f2bf(row[k0 + i]);
    r[i] = (short)v;
  }
  return r;
}

__device__ __forceinline__ short4 pack4(float4 v) {
  return make_short4((short)f2bf(v.x), (short)f2bf(v.y),
                     (short)f2bf(v.z), (short)f2bf(v.w));
}

// fast sigmoid / tanh: v_exp2 + v_rcp (no precise-div sequence)
__device__ __forceinline__ float sigr(float x) {
  float e = __builtin_amdgcn_exp2f(x * -1.44269504f);
  return __builtin_amdgcn_rcpf(1.0f + e);
}
__device__ __forceinline__ float tanhr(float x) {
  float e = __builtin_amdgcn_exp2f(x * -2.88539008f);
  return __fmaf_rn(2.0f, __builtin_amdgcn_rcpf(1.0f + e), -1.0f);
}

// ushort index of element (row b, col k) inside an A-frag-ordered tile:
// frag[k>>5][ b | (((k>>3)&3)<<4) ][ k&7 ]   (tile = 4*64*8 ushorts)
__device__ __forceinline__ int frag_idx(int b, int k) {
  return ((k >> 5) << 9) + ((b + (((k >> 3) & 3) << 4)) << 3) + (k & 7);
}

// ---------------------------------------------------------------------------
// Fused kernel. grid = 8 blocks (16 batches) x 512 threads (8 waves).
// Wave w owns e-strip [16w,16w+16); its 4 col-tiles are gates {i,f,g,o} of
// that strip -> all 4 gates of (b,e) land in ONE lane (no shuffles).
// Waves 0-3: emissions+Viterbi (lagged 1 step). Waves 4-7: x staging.
// h/x tiles live in LDS in MFMA A-fragment order (conflict-free b128 reads).
// ---------------------------------------------------------------------------
__global__ __launch_bounds__(512, 2) void lstm_crf_fused(
    const int* __restrict__ sent, const float* __restrict__ embed,
    const float* __restrict__ Wih, const float* __restrict__ Whh,
    const float* __restrict__ bih, const float* __restrict__ bhh,
    const float* __restrict__ h0, const float* __restrict__ c0,
    const float* __restrict__ Wtag, const float* __restrict__ btag,
    const float* __restrict__ trans, float* __restrict__ out)
{
  __shared__ unsigned char bp[256 * 192];                  // 48 KB nibble-packed
  __shared__ __align__(16) unsigned short hfrag[2][2048];  // 8 KB h, frag order
  __shared__ __align__(16) unsigned short xfrag[2][2048];  // 8 KB x, frag order
  __shared__ __align__(16) float vit[16 * 16];             // 1 KB trellis
  __shared__ __align__(16) float trl[KK * 16];             // trl[j*16+i]=trans[i][j]

  const int bg  = blockIdx.x;
  const int tid = threadIdx.x;
  const int w   = tid >> 6;         // wave 0..7
  const int l   = tid & 63;
  const int c   = l & 15;           // MFMA col within tile
  const int q   = l >> 4;           // row group (b = q*4+r)
  const bool vw = (w < 4);          // viterbi waves

  // ---- weights: 4 gate-tiles {i,f,g,o} of e-strip [16w,16w+16) ----
  const int ew = 16 * w + c;        // this lane's e (gate column within strip)
  bf16x8 wh[4][4], wx[4][4];
  float biasv[4];
  #pragma unroll
  for (int tt = 0; tt < 4; ++tt) {
    const int gcol = tt * HH + ew;
    biasv[tt] = bih[gcol] + bhh[gcol];
    #pragma unroll
    for (int kt = 0; kt < 4; ++kt) {
      const int k0 = kt * 32 + q * 8;
      wh[tt][kt] = load8_bf(Whh + (size_t)gcol * HH + k0);
      wx[tt][kt] = load8_bf_pad(Wih + (size_t)gcol * EE, k0, EE);
    }
  }

  // ---- cell state: lane (q,c) holds c for (b=q*4+r, e=ew), r=0..3 ----
  float cst[4];
  #pragma unroll
  for (int r = 0; r < 4; ++r)
    cst[r] = c0[(size_t)(bg * 16 + q * 4 + r) * HH + ew];

  // ---- emission weight fragments (registers, waves 0-3, tag col = c) ----
  bf16x8 we[4];
  #pragma unroll
  for (int kt = 0; kt < 4; ++kt) {
    #pragma unroll
    for (int i = 0; i < 8; ++i) we[kt][i] = 0;
  }
  float bt = 0.f;
  if (vw && c < KK) {
    #pragma unroll
    for (int kt = 0; kt < 4; ++kt)
      we[kt] = load8_bf(Wtag + (size_t)c * HH + kt * 32 + q * 8);
    bt = btag[c];
  }

  // ---- h0 -> hfrag[0] ----
  for (int idx = tid; idx < 2048; idx += 512) {
    int b = idx >> 7, k = idx & 127;
    hfrag[0][frag_idx(b, k)] = f2bf(h0[(size_t)(bg * 16 + b) * HH + k]);
  }
  // ---- transitions (transposed, padded) -> LDS ----
  if (tid < KK * KK) {
    int i = tid / KK, jj = tid - i * KK;
    trl[jj * 16 + i] = trans[tid];
  }

  // ---- x staging (waves 4-7): row sb, float4 cols kq0 and kq0+16 ----
  const bool stg = (w >= 4);
  const int sid = tid & 255;
  const int sb = sid >> 4, kq0 = sid & 15;
  const bool has2 = (kq0 < 9);          // (kq0+16)*4 < 100
  const int* sentb = sent + (size_t)(bg * 16 + sb) * TT;
  if (stg) {
    if (kq0 >= 9) {                     // zero tails k in [100,128), both bufs
      short4 z = make_short4(0, 0, 0, 0);
      int zo = frag_idx(sb, (kq0 + 16) * 4);
      *reinterpret_cast<short4*>(&xfrag[0][zo]) = z;
      *reinterpret_cast<short4*>(&xfrag[1][zo]) = z;
    }
    const float* er = embed + (size_t)sentb[0] * EE;     // x(0) direct
    float4 v0 = *reinterpret_cast<const float4*>(er + kq0 * 4);
    *reinterpret_cast<short4*>(&xfrag[0][frag_idx(sb, kq0 * 4)]) = pack4(v0);
    if (has2) {
      float4 v1 = *reinterpret_cast<const float4*>(er + (kq0 + 16) * 4);
      *reinterpret_cast<short4*>(&xfrag[0][frag_idx(sb, (kq0 + 16) * 4)]) = pack4(v1);
    }
  }
  float4 xv0 = {0.f, 0.f, 0.f, 0.f}, xv1 = {0.f, 0.f, 0.f, 0.f};
  if (stg) {                            // issue loads for x(1)
    const float* er = embed + (size_t)sentb[1] * EE;
    xv0 = *reinterpret_cast<const float4*>(er + kq0 * 4);
    if (has2) xv1 = *reinterpret_cast<const float4*>(er + (kq0 + 16) * 4);
  }

  // h write-back base: element (b=q*4+r, k=ew) of next h tile, r stride = 8 us
  const int hw_off = frag_idx(q * 4, ew);

  int nib = 0;
  __syncthreads();

  for (int s = 0; s <= TT; ++s) {
    const int rb = s & 1;

    // A fragments: h(s-1)-tile, frag-order -> base + kt*1024B, conflict-free
    bf16x8 ha[4];
    const bf16x8* hr = reinterpret_cast<const bf16x8*>(&hfrag[rb][0]) + l;
    #pragma unroll
    for (int kt = 0; kt < 4; ++kt) ha[kt] = hr[kt * 64];

    // ---- emissions (h after step s-1) + Viterbi t = s-1, waves 0-3 ----
    if (vw && s >= 1) {
      f32x4 accE = {0.f, 0.f, 0.f, 0.f};
      #pragma unroll
      for (int kt = 0; kt < 4; ++kt)
        accE = __builtin_amdgcn_mfma_f32_16x16x32_bf16(ha[kt], we[kt], accE, 0, 0, 0);
      float Ev = (w == 0 ? accE[0] : w == 1 ? accE[1] : w == 2 ? accE[2] : accE[3]) + bt;
      if (c < KK) {
        const int b = q * 4 + w;
        const int j = c;
        float nv;
        if (s == 1) {
          nv = Ev;
        } else {
          float4 v0 = *reinterpret_cast<const float4*>(&vit[b * 16]);
          float4 v1 = *reinterpret_cast<const float4*>(&vit[b * 16 + 4]);
          float4 v2 = *reinterpret_cast<const float4*>(&vit[b * 16 + 8]);
          float4 t0 = *reinterpret_cast<const float4*>(&trl[j * 16]);
          float4 t1 = *reinterpret_cast<const float4*>(&trl[j * 16 + 4]);
          float4 t2 = *reinterpret_cast<const float4*>(&trl[j * 16 + 8]);
          float cand[KK] = {v0.x + t0.x, v0.y + t0.y, v0.z + t0.z, v0.w + t0.w,
                            v1.x + t1.x, v1.y + t1.y, v1.z + t1.z, v1.w + t1.w,
                            v2.x + t2.x, v2.y + t2.y, v2.z + t2.z, v2.w + t2.w};
          float best = cand[0];
          int bi = 0;
          #pragma unroll
          for (int i = 1; i < KK; ++i)
            if (cand[i] > best) { best = cand[i]; bi = i; }   // first-max
          nv = Ev + best;
          const int t_ = s - 1;
          if (t_ & 1) bp[(t_ >> 1) * 192 + b * 12 + j] =
                          (unsigned char)(nib | (bi << 4));
          else        nib = bi;
        }
        vit[b * 16 + j] = nv;
      }
    }

    if (s < TT) {
      // x(s)-tile A fragments (frag-order, conflict-free)
      bf16x8 xa[4];
      const bf16x8* xr = reinterpret_cast<const bf16x8*>(&xfrag[rb][0]) + l;
      #pragma unroll
      for (int kt = 0; kt < 4; ++kt) xa[kt] = xr[kt * 64];

      // staging: write x(s+1), then issue loads for x(s+2)
      if (stg && s + 1 < TT) {
        unsigned short* xw = xfrag[rb ^ 1];
        *reinterpret_cast<short4*>(&xw[frag_idx(sb, kq0 * 4)]) = pack4(xv0);
        if (has2)
          *reinterpret_cast<short4*>(&xw[frag_idx(sb, (kq0 + 16) * 4)]) = pack4(xv1);
      }
      if (stg && s + 2 < TT) {
        const float* er = embed + (size_t)sentb[s + 2] * EE;
        xv0 = *reinterpret_cast<const float4*>(er + kq0 * 4);
        if (has2) xv1 = *reinterpret_cast<const float4*>(er + (kq0 + 16) * 4);
      }

      // ---- gate GEMM: bias + x@Wih^T + h@Whh^T, tiles = {i,f,g,o} ----
      f32x4 acc[4];
      #pragma unroll
      for (int tt = 0; tt < 4; ++tt) {
        acc[tt][0] = biasv[tt]; acc[tt][1] = biasv[tt];
        acc[tt][2] = biasv[tt]; acc[tt][3] = biasv[tt];
      }
      #pragma unroll
      for (int kt = 0; kt < 4; ++kt) {
        #pragma unroll
        for (int tt = 0; tt < 4; ++tt)
          acc[tt] = __builtin_amdgcn_mfma_f32_16x16x32_bf16(xa[kt], wx[tt][kt], acc[tt], 0, 0, 0);
      }
      #pragma unroll
      for (int kt = 0; kt < 4; ++kt) {
        #pragma unroll
        for (int tt = 0; tt < 4; ++tt)
          acc[tt] = __builtin_amdgcn_mfma_f32_16x16x32_bf16(ha[kt], wh[tt][kt], acc[tt], 0, 0, 0);
      }

      // ---- cell update: fully lane-local (i,f,g,o all in this lane) ----
      unsigned short* hwp = &hfrag[rb ^ 1][hw_off];
      #pragma unroll
      for (int r = 0; r < 4; ++r) {
        float si = sigr(acc[0][r]);
        float sf = sigr(acc[1][r]);
        float tg = tanhr(acc[2][r]);
        float so = sigr(acc[3][r]);
        cst[r] = __fmaf_rn(sf, cst[r], si * tg);
        hwp[r * 8] = f2bf(so * tanhr(cst[r]));
      }
    }
    __syncthreads();
  }

  // ---- scores + backtrace (16 parallel chains) ----
  unsigned char* pb = reinterpret_cast<unsigned char*>(hfrag);  // reuse 8 KB
  if (tid < 16) {
    int b = tid;
    float best = vit[b * 16];
    int tag = 0;
    for (int jj = 1; jj < KK; ++jj) {
      float v = vit[b * 16 + jj];
      if (v > best) { best = v; tag = jj; }
    }
    out[bg * 16 + b] = best;                    // scores
    pb[b * 512 + 511] = (unsigned char)tag;
    for (int t_ = TT - 1; t_ >= 1; --t_) {
      unsigned char byte = bp[(t_ >> 1) * 192 + b * 12 + tag];
      tag = (t_ & 1) ? (byte >> 4) & 15 : (byte & 15);
      pb[b * 512 + t_ - 1] = (unsigned char)tag;
    }
  }
  __syncthreads();

  #pragma unroll
  for (int i = 0; i < 16; ++i) {
    int idx = tid + i * 512;
    out[BB + (size_t)bg * 8192 + idx] = (float)pb[idx];
  }
}

// ---------------------------------------------------------------------------
extern "C" void kernel_launch(void* const* d_in, const int* in_sizes, int n_in,
                              void* d_out, int out_size, void* d_ws, size_t ws_size,
                              hipStream_t stream) {
  const int*   sent  = (const int*)d_in[0];
  const float* h0    = (const float*)d_in[1];
  const float* c0    = (const float*)d_in[2];
  const float* embed = (const float*)d_in[3];
  const float* Wih   = (const float*)d_in[4];
  const float* Whh   = (const float*)d_in[5];
  const float* bih   = (const float*)d_in[6];
  const float* bhh   = (const float*)d_in[7];
  const float* Wtag  = (const float*)d_in[8];
  const float* btag  = (const float*)d_in[9];
  const float* trans = (const float*)d_in[10];
  float* out = (float*)d_out;

  lstm_crf_fused<<<BB / 16, 512, 0, stream>>>(
      sent, embed, Wih, Whh, bih, bhh, h0, c0, Wtag, btag, trans, out);
}